// Round 1
// baseline (751.559 us; speedup 1.0000x reference)
//
#include <hip/hip_runtime.h>
#include <hip/hip_bf16.h>

#define N_NODES 10000
#define N_EDGES 320000
#define DIM     256
#define N_LAYERS 5
#define N_GRAPHS 128
#define RWSE_K  16

// ---------------- embedding ----------------
__global__ __launch_bounds__(256)
void embed_kernel(const int* __restrict__ feat_id,
                  const float* __restrict__ rwse,
                  const int* __restrict__ in_deg,
                  const float* __restrict__ w_val,
                  const float* __restrict__ b_val,
                  const float* __restrict__ w_rwse,
                  const float* __restrict__ b_rwse,
                  const float* __restrict__ deg_emb,
                  float* __restrict__ h) {
    int i = blockIdx.x;
    int d = threadIdx.x;
    __shared__ float r[RWSE_K];
    if (d < RWSE_K) r[d] = rwse[i * RWSE_K + d];
    __syncthreads();
    int hid = feat_id[i] & (DIM - 1);           // feat_id >= 0, remainder == mask
    int dg = in_deg[i];
    dg = dg < 0 ? 0 : (dg > 1000 ? 1000 : dg);
    float v = w_val[hid * DIM + d] + b_val[d] + b_rwse[d] + deg_emb[dg * DIM + d];
#pragma unroll
    for (int k = 0; k < RWSE_K; ++k) v += r[k] * w_rwse[k * DIM + d];
    h[i * DIM + d] = v;
}

// ---------------- CSR build ----------------
__global__ __launch_bounds__(256)
void count_kernel(const int* __restrict__ ei, int* __restrict__ rp) {
    int e = blockIdx.x * 256 + threadIdx.x;
    if (e < N_EDGES) atomicAdd(&rp[ei[N_EDGES + e] + 1], 1);
}

// single-block inclusive scan over rp[1..n]; rp[0] pre-zeroed
__global__ __launch_bounds__(1024)
void scan_kernel(int* __restrict__ rp, int n) {
    __shared__ int sh[1024];
    __shared__ int carry_sh;
    int tid = threadIdx.x;
    if (tid == 0) carry_sh = 0;
    __syncthreads();
    for (int base = 0; base < n; base += 1024) {
        int idx = base + tid;
        int v = (idx < n) ? rp[idx + 1] : 0;
        sh[tid] = v;
        __syncthreads();
        for (int off = 1; off < 1024; off <<= 1) {
            int t = (tid >= off) ? sh[tid - off] : 0;
            __syncthreads();
            sh[tid] += t;
            __syncthreads();
        }
        int incl = sh[tid];
        int carry = carry_sh;
        if (idx < n) rp[idx + 1] = incl + carry;
        __syncthreads();
        if (tid == 1023) carry_sh = carry + incl;
        __syncthreads();
    }
}

__global__ __launch_bounds__(256)
void cursor_kernel(const int* __restrict__ rp, int* __restrict__ cursor) {
    int i = blockIdx.x * 256 + threadIdx.x;
    if (i < N_NODES) cursor[i] = rp[i];
}

__global__ __launch_bounds__(256)
void fill_kernel(const int* __restrict__ ei, int* __restrict__ cursor,
                 int* __restrict__ cs) {
    int e = blockIdx.x * 256 + threadIdx.x;
    if (e < N_EDGES) {
        int d = ei[N_EDGES + e];
        int p = atomicAdd(&cursor[d], 1);
        cs[p] = ei[e];
    }
}

// ---------------- BN fold ----------------
__global__ __launch_bounds__(256)
void prep_kernel(const float* __restrict__ gamma, const float* __restrict__ beta,
                 const float* __restrict__ mean, const float* __restrict__ var,
                 const float* __restrict__ b2, float* __restrict__ scale,
                 float* __restrict__ shift) {
    int idx = blockIdx.x * DIM + threadIdx.x;
    float s = gamma[idx] * rsqrtf(var[idx] + 1e-5f);
    scale[idx] = s;
    shift[idx] = beta[idx] + (b2[idx] - mean[idx]) * s;
}

// ---------------- aggregation (CSR gather-sum) ----------------
// one wave per node; lane handles one float4 of the 256-float row
__global__ __launch_bounds__(256)
void agg_kernel(const float* __restrict__ h, const int* __restrict__ rp,
                const int* __restrict__ cs, const float* __restrict__ eps_gin,
                int layer, float* __restrict__ y) {
    int wave = threadIdx.x >> 6;
    int lane = threadIdx.x & 63;
    int i = blockIdx.x * 4 + wave;
    if (i >= N_NODES) return;
    float sc = 1.0f + eps_gin[layer];
    const float4* h4 = (const float4*)h;
    float4 a = h4[i * 64 + lane];
    float4 acc;
    acc.x = a.x * sc; acc.y = a.y * sc; acc.z = a.z * sc; acc.w = a.w * sc;
    int e0 = rp[i], e1 = rp[i + 1];
    for (int e = e0; e < e1; ++e) {
        int s = cs[e];
        float4 v = h4[s * 64 + lane];
        acc.x += v.x; acc.y += v.y; acc.z += v.z; acc.w += v.w;
    }
    ((float4*)y)[i * 64 + lane] = acc;
}

// ---------------- GEMM: C = epilogue(A @ W) ----------------
// A [nrows,256], W [256,256] (k-major rows), epilogue:
//   scale!=null: relu(acc*scale[c] + shift[c])   (BN fold, bias folded into shift)
//   scale==null: relu(acc + shift[c])            (bias+ReLU)
#define BM 64
#define BN 64
#define BK 32
#define LPAD 4

__global__ __launch_bounds__(256)
void gemm_kernel(const float* __restrict__ A, const float* __restrict__ W,
                 const float* __restrict__ scale, const float* __restrict__ shift,
                 float* __restrict__ C, int nrows) {
    __shared__ __align__(16) float As[BK][BM + LPAD];
    __shared__ __align__(16) float Bs[BK][BN + LPAD];
    int tx = threadIdx.x;
    int row0 = blockIdx.x * BM;
    int col0 = blockIdx.y * BN;
    int tr = (tx >> 4) << 2;     // 0..60 step 4
    int tc = (tx & 15) << 2;     // 0..60 step 4
    int am = tx >> 3;            // 0..31
    int ak = (tx & 7) << 2;      // 0..28 step 4
    int bk = tx >> 4;            // 0..15
    int bc = (tx & 15) << 2;     // 0..60 step 4

    float acc[4][4];
#pragma unroll
    for (int i = 0; i < 4; ++i)
#pragma unroll
        for (int j = 0; j < 4; ++j) acc[i][j] = 0.f;

    for (int k0 = 0; k0 < DIM; k0 += BK) {
        // stage A tile (64x32) transposed into As[k][m]
#pragma unroll
        for (int rep = 0; rep < 2; ++rep) {
            int m = am + rep * 32;
            int row = row0 + m;
            float4 av = make_float4(0.f, 0.f, 0.f, 0.f);
            if (row < nrows) av = *(const float4*)&A[row * DIM + k0 + ak];
            As[ak + 0][m] = av.x;
            As[ak + 1][m] = av.y;
            As[ak + 2][m] = av.z;
            As[ak + 3][m] = av.w;
        }
        // stage B tile (32x64)
#pragma unroll
        for (int rep = 0; rep < 2; ++rep) {
            int kk = bk + rep * 16;
            float4 bv = *(const float4*)&W[(k0 + kk) * DIM + col0 + bc];
            *(float4*)&Bs[kk][bc] = bv;
        }
        __syncthreads();
#pragma unroll
        for (int kk = 0; kk < BK; ++kk) {
            float4 af = *(const float4*)&As[kk][tr];
            float4 bf = *(const float4*)&Bs[kk][tc];
            float av[4] = {af.x, af.y, af.z, af.w};
            float bv[4] = {bf.x, bf.y, bf.z, bf.w};
#pragma unroll
            for (int i = 0; i < 4; ++i)
#pragma unroll
                for (int j = 0; j < 4; ++j) acc[i][j] = fmaf(av[i], bv[j], acc[i][j]);
        }
        __syncthreads();
    }
    // epilogue
#pragma unroll
    for (int i = 0; i < 4; ++i) {
        int r = row0 + tr + i;
        if (r < nrows) {
            float4 o;
            float* ov = &o.x;
#pragma unroll
            for (int j = 0; j < 4; ++j) {
                int c = col0 + tc + j;
                float v = acc[i][j];
                v = scale ? v * scale[c] + shift[c] : v + shift[c];
                ov[j] = fmaxf(v, 0.f);
            }
            *(float4*)&C[r * DIM + col0 + tc] = o;
        }
    }
}

// ---------------- pooling ----------------
__global__ __launch_bounds__(256)
void pool_kernel(const float* __restrict__ h, const int* __restrict__ batch,
                 float* __restrict__ pool, int* __restrict__ cnt,
                 float* __restrict__ out_h) {
    int i = blockIdx.x;
    int d = threadIdx.x;
    float v = h[i * DIM + d];
    out_h[i * DIM + d] = v;
    int b = batch[i];
    atomicAdd(&pool[b * DIM + d], v);
    if (d == 0) atomicAdd(&cnt[b], 1);
}

__global__ __launch_bounds__(256)
void final_kernel(const float* __restrict__ pool, const int* __restrict__ cnt,
                  float* __restrict__ out) {
    int g = blockIdx.x;
    int d = threadIdx.x;
    float c = (float)cnt[g];
    if (c < 1.f) c = 1.f;
    out[g * DIM + d] = pool[g * DIM + d] / c;
}

// ---------------- launch ----------------
extern "C" void kernel_launch(void* const* d_in, const int* in_sizes, int n_in,
                              void* d_out, int out_size, void* d_ws, size_t ws_size,
                              hipStream_t stream) {
    const int*   feat_id  = (const int*)d_in[0];
    const int*   ei       = (const int*)d_in[1];   // [2,E]: src=ei[0..E), dst=ei[E..2E)
    const int*   batch    = (const int*)d_in[2];
    const float* rwse     = (const float*)d_in[3];
    const int*   in_deg   = (const int*)d_in[4];
    const float* w_val    = (const float*)d_in[5];
    const float* b_val    = (const float*)d_in[6];
    const float* w_rwse   = (const float*)d_in[7];
    const float* b_rwse   = (const float*)d_in[8];
    const float* deg_emb  = (const float*)d_in[9];
    const float* mlp_w1   = (const float*)d_in[10];
    const float* mlp_b1   = (const float*)d_in[11];
    const float* mlp_w2   = (const float*)d_in[12];
    const float* mlp_b2   = (const float*)d_in[13];
    const float* bn_gamma = (const float*)d_in[14];
    const float* bn_beta  = (const float*)d_in[15];
    const float* bn_mean  = (const float*)d_in[16];
    const float* bn_var   = (const float*)d_in[17];
    const float* eps_gin  = (const float*)d_in[18];

    float* out = (float*)d_out;

    // workspace carve-up (all recomputed every call; harness poisons ws)
    char* w = (char*)d_ws;
    float* h  = (float*)w;                         // N*D
    float* y  = h + (size_t)N_NODES * DIM;         // N*D
    float* t  = y + (size_t)N_NODES * DIM;         // N*D
    int* rp     = (int*)(t + (size_t)N_NODES * DIM);  // N+1
    int* cursor = rp + (N_NODES + 2);                 // N
    int* cs     = cursor + N_NODES;                   // E
    float* pool = (float*)(cs + N_EDGES);             // G*D
    int* cnt    = (int*)(pool + N_GRAPHS * DIM);      // G
    float* bnsc = (float*)(cnt + N_GRAPHS);           // L*D
    float* bnsh = bnsc + N_LAYERS * DIM;              // L*D

    hipMemsetAsync(rp, 0, (N_NODES + 1) * sizeof(int), stream);
    hipMemsetAsync(pool, 0, (N_GRAPHS * DIM + N_GRAPHS) * sizeof(float), stream);

    embed_kernel<<<N_NODES, 256, 0, stream>>>(feat_id, rwse, in_deg, w_val, b_val,
                                              w_rwse, b_rwse, deg_emb, h);
    count_kernel<<<(N_EDGES + 255) / 256, 256, 0, stream>>>(ei, rp);
    scan_kernel<<<1, 1024, 0, stream>>>(rp, N_NODES);
    cursor_kernel<<<(N_NODES + 255) / 256, 256, 0, stream>>>(rp, cursor);
    fill_kernel<<<(N_EDGES + 255) / 256, 256, 0, stream>>>(ei, cursor, cs);
    prep_kernel<<<N_LAYERS, 256, 0, stream>>>(bn_gamma, bn_beta, bn_mean, bn_var,
                                              mlp_b2, bnsc, bnsh);

    dim3 ggrid((N_NODES + BM - 1) / BM, DIM / BN);
    for (int l = 0; l < N_LAYERS; ++l) {
        agg_kernel<<<(N_NODES + 3) / 4, 256, 0, stream>>>(h, rp, cs, eps_gin, l, y);
        gemm_kernel<<<ggrid, 256, 0, stream>>>(y, mlp_w1 + (size_t)l * DIM * DIM,
                                               nullptr, mlp_b1 + l * DIM, t, N_NODES);
        gemm_kernel<<<ggrid, 256, 0, stream>>>(t, mlp_w2 + (size_t)l * DIM * DIM,
                                               bnsc + l * DIM, bnsh + l * DIM, h, N_NODES);
    }

    pool_kernel<<<N_NODES, 256, 0, stream>>>(h, batch, pool, cnt, out + N_GRAPHS * DIM);
    final_kernel<<<N_GRAPHS, 256, 0, stream>>>(pool, cnt, out);
}

// Round 3
// 531.659 us; speedup vs baseline: 1.4136x; 1.4136x over previous
//
#include <hip/hip_runtime.h>
#include <hip/hip_bf16.h>

#define N_NODES 10000
#define N_EDGES 320000
#define DIM     256
#define N_LAYERS 5
#define N_GRAPHS 128
#define RWSE_K  16

typedef __bf16 bf16_t;
typedef bf16_t bf16x8 __attribute__((ext_vector_type(8)));
typedef float  f32x4  __attribute__((ext_vector_type(4)));

__device__ inline ushort f2bf(float f) {
    union { float f; unsigned u; } v; v.f = f;
    unsigned r = v.u + 0x7fff + ((v.u >> 16) & 1);
    return (ushort)(r >> 16);
}
__device__ inline float bfbits2f(unsigned hi16) {   // hi16 = bf16 bits already in high half
    union { unsigned u; float f; } v; v.u = hi16;
    return v.f;
}

// ---------------- embedding (writes f32 h + bf16 mirror) ----------------
__global__ __launch_bounds__(256)
void embed_kernel(const int* __restrict__ feat_id,
                  const float* __restrict__ rwse,
                  const int* __restrict__ in_deg,
                  const float* __restrict__ w_val,
                  const float* __restrict__ b_val,
                  const float* __restrict__ w_rwse,
                  const float* __restrict__ b_rwse,
                  const float* __restrict__ deg_emb,
                  float* __restrict__ h, ushort* __restrict__ hb) {
    int i = blockIdx.x;
    int d = threadIdx.x;
    __shared__ float r[RWSE_K];
    if (d < RWSE_K) r[d] = rwse[i * RWSE_K + d];
    __syncthreads();
    int hid = feat_id[i] & (DIM - 1);
    int dg = in_deg[i];
    dg = dg < 0 ? 0 : (dg > 1000 ? 1000 : dg);
    float v = w_val[hid * DIM + d] + b_val[d] + b_rwse[d] + deg_emb[dg * DIM + d];
#pragma unroll
    for (int k = 0; k < RWSE_K; ++k) v += r[k] * w_rwse[k * DIM + d];
    h[i * DIM + d] = v;
    hb[i * DIM + d] = f2bf(v);
}

// ---------------- CSR build ----------------
__global__ __launch_bounds__(256)
void count_kernel(const int* __restrict__ ei, int* __restrict__ rp) {
    int e = blockIdx.x * 256 + threadIdx.x;
    if (e < N_EDGES) atomicAdd(&rp[ei[N_EDGES + e] + 1], 1);
}

__global__ __launch_bounds__(1024)
void scan_kernel(int* __restrict__ rp, int n) {
    __shared__ int sh[1024];
    __shared__ int carry_sh;
    int tid = threadIdx.x;
    if (tid == 0) carry_sh = 0;
    __syncthreads();
    for (int base = 0; base < n; base += 1024) {
        int idx = base + tid;
        int v = (idx < n) ? rp[idx + 1] : 0;
        sh[tid] = v;
        __syncthreads();
        for (int off = 1; off < 1024; off <<= 1) {
            int t = (tid >= off) ? sh[tid - off] : 0;
            __syncthreads();
            sh[tid] += t;
            __syncthreads();
        }
        int incl = sh[tid];
        int carry = carry_sh;
        if (idx < n) rp[idx + 1] = incl + carry;
        __syncthreads();
        if (tid == 1023) carry_sh = carry + incl;
        __syncthreads();
    }
}

__global__ __launch_bounds__(256)
void cursor_kernel(const int* __restrict__ rp, int* __restrict__ cursor) {
    int i = blockIdx.x * 256 + threadIdx.x;
    if (i < N_NODES) cursor[i] = rp[i];
}

__global__ __launch_bounds__(256)
void fill_kernel(const int* __restrict__ ei, int* __restrict__ cursor,
                 int* __restrict__ cs) {
    int e = blockIdx.x * 256 + threadIdx.x;
    if (e < N_EDGES) {
        int d = ei[N_EDGES + e];
        int p = atomicAdd(&cursor[d], 1);
        cs[p] = ei[e];
    }
}

// ---------------- BN fold ----------------
__global__ __launch_bounds__(256)
void prep_kernel(const float* __restrict__ gamma, const float* __restrict__ beta,
                 const float* __restrict__ mean, const float* __restrict__ var,
                 const float* __restrict__ b2, float* __restrict__ scale,
                 float* __restrict__ shift) {
    int idx = blockIdx.x * DIM + threadIdx.x;
    float s = gamma[idx] * rsqrtf(var[idx] + 1e-5f);
    scale[idx] = s;
    shift[idx] = beta[idx] + (b2[idx] - mean[idx]) * s;
}

// ---------------- weight transpose + bf16 convert: Wt[n][k] = W[k][n] ----------------
__global__ __launch_bounds__(256)
void wconv_kernel(const float* __restrict__ w1, const float* __restrict__ w2,
                  ushort* __restrict__ wt1, ushort* __restrict__ wt2) {
    int l = blockIdx.z;
    const float* W  = (blockIdx.y ? w2  : w1)  + (size_t)l * DIM * DIM;
    ushort*      Wt = (blockIdx.y ? wt2 : wt1) + (size_t)l * DIM * DIM;
    int tile = blockIdx.x;
    int k0 = (tile >> 3) * 32, n0 = (tile & 7) * 32;
    __shared__ float t[32][33];
    int tx = threadIdx.x & 31, ty = threadIdx.x >> 5;   // ty 0..7
#pragma unroll
    for (int j = 0; j < 4; ++j)
        t[ty + j * 8][tx] = W[(k0 + ty + j * 8) * DIM + n0 + tx];
    __syncthreads();
#pragma unroll
    for (int j = 0; j < 4; ++j)
        Wt[(n0 + ty + j * 8) * DIM + k0 + tx] = f2bf(t[tx][ty + j * 8]);
}

// ---------------- aggregation (CSR gather-sum, bf16 neighbors) ----------------
// one wave per node; lane covers 4 channels (4 bf16 = 8B per neighbor row)
__global__ __launch_bounds__(256)
void agg_kernel(const float* __restrict__ h, const ushort* __restrict__ hb,
                const int* __restrict__ rp, const int* __restrict__ cs,
                const float* __restrict__ eps_gin, int layer,
                ushort* __restrict__ y) {
    int wave = threadIdx.x >> 6;
    int lane = threadIdx.x & 63;
    int i = blockIdx.x * 4 + wave;
    if (i >= N_NODES) return;
    float sc = 1.0f + eps_gin[layer];
    const float4* h4 = (const float4*)h;
    float4 a = h4[i * 64 + lane];
    float acc0 = a.x * sc, acc1 = a.y * sc, acc2 = a.z * sc, acc3 = a.w * sc;
    const uint2* hb2 = (const uint2*)hb;   // row = 64 uint2
    int e0 = rp[i], e1 = rp[i + 1];
    for (int e = e0; e < e1; ++e) {
        int s = cs[e];
        uint2 v = hb2[(size_t)s * 64 + lane];
        acc0 += bfbits2f(v.x << 16);
        acc1 += bfbits2f(v.x & 0xffff0000u);
        acc2 += bfbits2f(v.y << 16);
        acc3 += bfbits2f(v.y & 0xffff0000u);
    }
    uint lo = (uint)f2bf(acc0) | ((uint)f2bf(acc1) << 16);
    uint hi = (uint)f2bf(acc2) | ((uint)f2bf(acc3) << 16);
    ((uint2*)y)[i * 64 + lane] = make_uint2(lo, hi);
}

// ---------------- bf16 MFMA GEMM: C = epilogue(A @ W) ----------------
// A [nrows,256] bf16 row-major; Wt [256,256] bf16 as Wt[n][k].
// epilogue: scale!=null -> relu(acc*scale[c]+shift[c]) ; else relu(acc+shift[c])
// outputs: C (f32, optional) and Cb (bf16, optional)
#define GBM 64
#define GBN 64
#define GBK 32
#define KPAD 8   // ushort pad -> 16B, keeps b128 alignment

__global__ __launch_bounds__(256)
void gemm_kernel(const ushort* __restrict__ A, const ushort* __restrict__ Wt,
                 const float* __restrict__ scale, const float* __restrict__ shift,
                 float* __restrict__ C, ushort* __restrict__ Cb, int nrows) {
    __shared__ __align__(16) ushort As[GBM][GBK + KPAD];
    __shared__ __align__(16) ushort Bs[GBN][GBK + KPAD];
    int tx = threadIdx.x;
    int row0 = blockIdx.x * GBM;
    int col0 = blockIdx.y * GBN;
    int wave = tx >> 6;
    int lane = tx & 63;
    int quad = lane >> 4;
    int l16  = lane & 15;
    int wm = (wave & 1) * 32;
    int wn = (wave >> 1) * 32;

    // staging map: thread t loads 8 bf16 (16B): row = t>>2, kcol = (t&3)*8
    int srow = tx >> 2;
    int skol = (tx & 3) * 8;

    f32x4 acc[2][2];
#pragma unroll
    for (int i = 0; i < 2; ++i)
#pragma unroll
        for (int j = 0; j < 2; ++j) acc[i][j] = (f32x4){0.f, 0.f, 0.f, 0.f};

    for (int k0 = 0; k0 < DIM; k0 += GBK) {
        int arow = row0 + srow;
        uint4 av = make_uint4(0u, 0u, 0u, 0u);
        if (arow < nrows) av = *(const uint4*)&A[(size_t)arow * DIM + k0 + skol];
        *(uint4*)&As[srow][skol] = av;
        uint4 bv = *(const uint4*)&Wt[(size_t)(col0 + srow) * DIM + k0 + skol];
        *(uint4*)&Bs[srow][skol] = bv;
        __syncthreads();

        bf16x8 af0 = *(const bf16x8*)&As[wm + l16][quad * 8];
        bf16x8 af1 = *(const bf16x8*)&As[wm + 16 + l16][quad * 8];
        bf16x8 bf0 = *(const bf16x8*)&Bs[wn + l16][quad * 8];
        bf16x8 bf1 = *(const bf16x8*)&Bs[wn + 16 + l16][quad * 8];
        acc[0][0] = __builtin_amdgcn_mfma_f32_16x16x32_bf16(af0, bf0, acc[0][0], 0, 0, 0);
        acc[0][1] = __builtin_amdgcn_mfma_f32_16x16x32_bf16(af0, bf1, acc[0][1], 0, 0, 0);
        acc[1][0] = __builtin_amdgcn_mfma_f32_16x16x32_bf16(af1, bf0, acc[1][0], 0, 0, 0);
        acc[1][1] = __builtin_amdgcn_mfma_f32_16x16x32_bf16(af1, bf1, acc[1][1], 0, 0, 0);
        __syncthreads();
    }

    // epilogue: C/D layout col=lane&15, row=quad*4+reg
#pragma unroll
    for (int ti = 0; ti < 2; ++ti) {
#pragma unroll
        for (int tj = 0; tj < 2; ++tj) {
            int col = col0 + wn + tj * 16 + l16;
            float sc = scale ? scale[col] : 1.f;
            float sh = shift[col];
#pragma unroll
            for (int r = 0; r < 4; ++r) {
                int row = row0 + wm + ti * 16 + quad * 4 + r;
                if (row < nrows) {
                    float v = acc[ti][tj][r];
                    v = scale ? v * sc + sh : v + sh;
                    v = fmaxf(v, 0.f);
                    if (C)  C[(size_t)row * DIM + col] = v;
                    if (Cb) Cb[(size_t)row * DIM + col] = f2bf(v);
                }
            }
        }
    }
}

// ---------------- pooling ----------------
__global__ __launch_bounds__(256)
void pool_kernel(const float* __restrict__ h, const int* __restrict__ batch,
                 float* __restrict__ pool, int* __restrict__ cnt,
                 float* __restrict__ out_h) {
    int i = blockIdx.x;
    int d = threadIdx.x;
    float v = h[i * DIM + d];
    out_h[i * DIM + d] = v;
    int b = batch[i];
    atomicAdd(&pool[b * DIM + d], v);
    if (d == 0) atomicAdd(&cnt[b], 1);
}

__global__ __launch_bounds__(256)
void final_kernel(const float* __restrict__ pool, const int* __restrict__ cnt,
                  float* __restrict__ out) {
    int g = blockIdx.x;
    int d = threadIdx.x;
    float c = (float)cnt[g];
    if (c < 1.f) c = 1.f;
    out[g * DIM + d] = pool[g * DIM + d] / c;
}

// ---------------- launch ----------------
extern "C" void kernel_launch(void* const* d_in, const int* in_sizes, int n_in,
                              void* d_out, int out_size, void* d_ws, size_t ws_size,
                              hipStream_t stream) {
    const int*   feat_id  = (const int*)d_in[0];
    const int*   ei       = (const int*)d_in[1];
    const int*   batch    = (const int*)d_in[2];
    const float* rwse     = (const float*)d_in[3];
    const int*   in_deg   = (const int*)d_in[4];
    const float* w_val    = (const float*)d_in[5];
    const float* b_val    = (const float*)d_in[6];
    const float* w_rwse   = (const float*)d_in[7];
    const float* b_rwse   = (const float*)d_in[8];
    const float* deg_emb  = (const float*)d_in[9];
    const float* mlp_w1   = (const float*)d_in[10];
    const float* mlp_b1   = (const float*)d_in[11];
    const float* mlp_w2   = (const float*)d_in[12];
    const float* mlp_b2   = (const float*)d_in[13];
    const float* bn_gamma = (const float*)d_in[14];
    const float* bn_beta  = (const float*)d_in[15];
    const float* bn_mean  = (const float*)d_in[16];
    const float* bn_var   = (const float*)d_in[17];
    const float* eps_gin  = (const float*)d_in[18];

    float* out = (float*)d_out;

    char* w = (char*)d_ws;
    float*  h   = (float*)w;                              // N*D f32
    ushort* hb  = (ushort*)(h + (size_t)N_NODES * DIM);   // N*D bf16
    ushort* y   = hb + (size_t)N_NODES * DIM;             // N*D bf16
    ushort* t   = y + (size_t)N_NODES * DIM;              // N*D bf16
    ushort* wt1 = t + (size_t)N_NODES * DIM;              // L*D*D bf16
    ushort* wt2 = wt1 + (size_t)N_LAYERS * DIM * DIM;     // L*D*D bf16
    int* rp     = (int*)(wt2 + (size_t)N_LAYERS * DIM * DIM); // N+1
    int* cursor = rp + (N_NODES + 2);
    int* cs     = cursor + N_NODES;                       // E
    float* pool = (float*)(cs + N_EDGES);                 // G*D
    int* cnt    = (int*)(pool + N_GRAPHS * DIM);          // G
    float* bnsc = (float*)(cnt + N_GRAPHS);               // L*D
    float* bnsh = bnsc + N_LAYERS * DIM;                  // L*D

    hipMemsetAsync(rp, 0, (N_NODES + 1) * sizeof(int), stream);
    hipMemsetAsync(pool, 0, (N_GRAPHS * DIM + N_GRAPHS) * sizeof(float), stream);

    embed_kernel<<<N_NODES, 256, 0, stream>>>(feat_id, rwse, in_deg, w_val, b_val,
                                              w_rwse, b_rwse, deg_emb, h, hb);
    count_kernel<<<(N_EDGES + 255) / 256, 256, 0, stream>>>(ei, rp);
    scan_kernel<<<1, 1024, 0, stream>>>(rp, N_NODES);
    cursor_kernel<<<(N_NODES + 255) / 256, 256, 0, stream>>>(rp, cursor);
    fill_kernel<<<(N_EDGES + 255) / 256, 256, 0, stream>>>(ei, cursor, cs);
    prep_kernel<<<N_LAYERS, 256, 0, stream>>>(bn_gamma, bn_beta, bn_mean, bn_var,
                                              mlp_b2, bnsc, bnsh);
    wconv_kernel<<<dim3(64, 2, N_LAYERS), 256, 0, stream>>>(mlp_w1, mlp_w2, wt1, wt2);

    dim3 ggrid((N_NODES + GBM - 1) / GBM, DIM / GBN);
    for (int l = 0; l < N_LAYERS; ++l) {
        agg_kernel<<<(N_NODES + 3) / 4, 256, 0, stream>>>(h, hb, rp, cs, eps_gin, l, y);
        gemm_kernel<<<ggrid, 256, 0, stream>>>(y, wt1 + (size_t)l * DIM * DIM,
                                               nullptr, mlp_b1 + l * DIM,
                                               nullptr, t, N_NODES);
        gemm_kernel<<<ggrid, 256, 0, stream>>>(t, wt2 + (size_t)l * DIM * DIM,
                                               bnsc + l * DIM, bnsh + l * DIM,
                                               h, hb, N_NODES);
    }

    pool_kernel<<<N_NODES, 256, 0, stream>>>(h, batch, pool, cnt, out + N_GRAPHS * DIM);
    final_kernel<<<N_GRAPHS, 256, 0, stream>>>(pool, cnt, out);
}

// Round 4
// 410.094 us; speedup vs baseline: 1.8327x; 1.2964x over previous
//
#include <hip/hip_runtime.h>
#include <hip/hip_bf16.h>

#define N_NODES 10000
#define N_EDGES 320000
#define DIM     256
#define N_LAYERS 5
#define N_GRAPHS 128
#define RWSE_K  16

typedef __bf16 bf16_t;
typedef bf16_t bf16x8 __attribute__((ext_vector_type(8)));
typedef float  f32x4  __attribute__((ext_vector_type(4)));

__device__ inline ushort f2bf(float f) {
    union { float f; unsigned u; } v; v.f = f;
    unsigned r = v.u + 0x7fff + ((v.u >> 16) & 1);
    return (ushort)(r >> 16);
}
__device__ inline float bfbits2f(unsigned hi16) {
    union { unsigned u; float f; } v; v.u = hi16;
    return v.f;
}

// ---------------- embedding (writes f32 h + bf16 mirror) ----------------
__global__ __launch_bounds__(256)
void embed_kernel(const int* __restrict__ feat_id,
                  const float* __restrict__ rwse,
                  const int* __restrict__ in_deg,
                  const float* __restrict__ w_val,
                  const float* __restrict__ b_val,
                  const float* __restrict__ w_rwse,
                  const float* __restrict__ b_rwse,
                  const float* __restrict__ deg_emb,
                  float* __restrict__ h, ushort* __restrict__ hb) {
    int i = blockIdx.x;
    int d = threadIdx.x;
    __shared__ float r[RWSE_K];
    if (d < RWSE_K) r[d] = rwse[i * RWSE_K + d];
    __syncthreads();
    int hid = feat_id[i] & (DIM - 1);
    int dg = in_deg[i];
    dg = dg < 0 ? 0 : (dg > 1000 ? 1000 : dg);
    float v = w_val[hid * DIM + d] + b_val[d] + b_rwse[d] + deg_emb[dg * DIM + d];
#pragma unroll
    for (int k = 0; k < RWSE_K; ++k) v += r[k] * w_rwse[k * DIM + d];
    h[i * DIM + d] = v;
    hb[i * DIM + d] = f2bf(v);
}

// ---------------- CSR build ----------------
__global__ __launch_bounds__(256)
void count_kernel(const int* __restrict__ ei, int* __restrict__ cnt_arr) {
    int e = blockIdx.x * 256 + threadIdx.x;
    if (e < N_EDGES) atomicAdd(&cnt_arr[ei[N_EDGES + e]], 1);
}

// exclusive scan of cnt_arr into cur (single block, wave-shuffle based)
__global__ __launch_bounds__(1024)
void scan_kernel(const int* __restrict__ cnt_arr, int* __restrict__ cur, int n) {
    __shared__ int wsum[16];
    __shared__ int carry_sh;
    int tid = threadIdx.x, wave = tid >> 6, lane = tid & 63;
    if (tid == 0) carry_sh = 0;
    __syncthreads();
    for (int base = 0; base < n; base += 1024) {
        int idx = base + tid;
        int v = (idx < n) ? cnt_arr[idx] : 0;
        int s = v;
#pragma unroll
        for (int off = 1; off < 64; off <<= 1) {
            int t = __shfl_up(s, off, 64);
            if (lane >= off) s += t;
        }
        if (lane == 63) wsum[wave] = s;
        __syncthreads();
        if (wave == 0) {
            int ws = (lane < 16) ? wsum[lane] : 0;
#pragma unroll
            for (int off = 1; off < 16; off <<= 1) {
                int t = __shfl_up(ws, off, 64);
                if (lane >= off) ws += t;
            }
            if (lane < 16) wsum[lane] = ws;
        }
        __syncthreads();
        int excl = s - v + (wave ? wsum[wave - 1] : 0) + carry_sh;
        if (idx < n) cur[idx] = excl;
        __syncthreads();
        if (tid == 0) carry_sh += wsum[15];
        __syncthreads();
    }
}

// fill: atomically bump cur[d]; after this kernel cur[i] == end offset of node i
__global__ __launch_bounds__(256)
void fill_kernel(const int* __restrict__ ei, int* __restrict__ cur,
                 int* __restrict__ cs) {
    int e = blockIdx.x * 256 + threadIdx.x;
    if (e < N_EDGES) {
        int d = ei[N_EDGES + e];
        int p = atomicAdd(&cur[d], 1);
        cs[p] = ei[e];
    }
}

// ---------------- weight transpose + bf16 convert + BN fold (merged) ----------------
__global__ __launch_bounds__(256)
void wconv_prep_kernel(const float* __restrict__ w1, const float* __restrict__ w2,
                       ushort* __restrict__ wt1, ushort* __restrict__ wt2,
                       const float* __restrict__ gamma, const float* __restrict__ beta,
                       const float* __restrict__ mean, const float* __restrict__ var,
                       const float* __restrict__ b2, float* __restrict__ scale,
                       float* __restrict__ shift) {
    int l = blockIdx.z;
    if (blockIdx.x == 64) {               // prep block
        if (blockIdx.y == 0) {
            int idx = l * DIM + threadIdx.x;
            float s = gamma[idx] * rsqrtf(var[idx] + 1e-5f);
            scale[idx] = s;
            shift[idx] = beta[idx] + (b2[idx] - mean[idx]) * s;
        }
        return;
    }
    const float* W  = (blockIdx.y ? w2  : w1)  + (size_t)l * DIM * DIM;
    ushort*      Wt = (blockIdx.y ? wt2 : wt1) + (size_t)l * DIM * DIM;
    int tile = blockIdx.x;
    int k0 = (tile >> 3) * 32, n0 = (tile & 7) * 32;
    __shared__ float t[32][33];
    int tx = threadIdx.x & 31, ty = threadIdx.x >> 5;
#pragma unroll
    for (int j = 0; j < 4; ++j)
        t[ty + j * 8][tx] = W[(k0 + ty + j * 8) * DIM + n0 + tx];
    __syncthreads();
#pragma unroll
    for (int j = 0; j < 4; ++j)
        Wt[(n0 + ty + j * 8) * DIM + k0 + tx] = f2bf(t[tx][ty + j * 8]);
}

// ---------------- aggregation (CSR gather-sum, bf16 neighbors, 4x MLP) ----------------
// one wave per node; lane covers 4 channels (8B per neighbor row);
// edge indices batched 64-wide via coalesced load + shfl broadcast;
// 4 independent row loads in flight per iteration.
__global__ __launch_bounds__(256)
void agg_kernel(const float* __restrict__ h, const ushort* __restrict__ hb,
                const int* __restrict__ cur, const int* __restrict__ cs,
                const float* __restrict__ eps_gin, int layer,
                ushort* __restrict__ y) {
    int wave = threadIdx.x >> 6;
    int lane = threadIdx.x & 63;
    int i = blockIdx.x * 4 + wave;
    if (i >= N_NODES) return;
    float sc = 1.0f + eps_gin[layer];
    const float4* h4 = (const float4*)h;
    float4 a = h4[i * 64 + lane];
    float acc0 = a.x * sc, acc1 = a.y * sc, acc2 = a.z * sc, acc3 = a.w * sc;
    const uint2* hb2 = (const uint2*)hb;
    int e0 = i ? cur[i - 1] : 0;
    int e1 = cur[i];
    for (int base = e0; base < e1; base += 64) {
        int rem = e1 - base;
        int cnt = rem < 64 ? rem : 64;
        int idx = (base + lane < e1) ? cs[base + lane] : 0;
        int j = 0;
        for (; j + 4 <= cnt; j += 4) {
            int s0 = __shfl(idx, j, 64);
            int s1 = __shfl(idx, j + 1, 64);
            int s2 = __shfl(idx, j + 2, 64);
            int s3 = __shfl(idx, j + 3, 64);
            uint2 v0 = hb2[(size_t)s0 * 64 + lane];
            uint2 v1 = hb2[(size_t)s1 * 64 + lane];
            uint2 v2 = hb2[(size_t)s2 * 64 + lane];
            uint2 v3 = hb2[(size_t)s3 * 64 + lane];
            acc0 += bfbits2f(v0.x << 16); acc1 += bfbits2f(v0.x & 0xffff0000u);
            acc2 += bfbits2f(v0.y << 16); acc3 += bfbits2f(v0.y & 0xffff0000u);
            acc0 += bfbits2f(v1.x << 16); acc1 += bfbits2f(v1.x & 0xffff0000u);
            acc2 += bfbits2f(v1.y << 16); acc3 += bfbits2f(v1.y & 0xffff0000u);
            acc0 += bfbits2f(v2.x << 16); acc1 += bfbits2f(v2.x & 0xffff0000u);
            acc2 += bfbits2f(v2.y << 16); acc3 += bfbits2f(v2.y & 0xffff0000u);
            acc0 += bfbits2f(v3.x << 16); acc1 += bfbits2f(v3.x & 0xffff0000u);
            acc2 += bfbits2f(v3.y << 16); acc3 += bfbits2f(v3.y & 0xffff0000u);
        }
        for (; j < cnt; ++j) {
            int s = __shfl(idx, j, 64);
            uint2 v = hb2[(size_t)s * 64 + lane];
            acc0 += bfbits2f(v.x << 16); acc1 += bfbits2f(v.x & 0xffff0000u);
            acc2 += bfbits2f(v.y << 16); acc3 += bfbits2f(v.y & 0xffff0000u);
        }
    }
    uint lo = (uint)f2bf(acc0) | ((uint)f2bf(acc1) << 16);
    uint hi = (uint)f2bf(acc2) | ((uint)f2bf(acc3) << 16);
    ((uint2*)y)[i * 64 + lane] = make_uint2(lo, hi);
}

// ---------------- fused MLP: H = BN(ReLU(A@W1+b1)@W2) -> ReLU ----------------
// A [nrows,256] bf16; Wt1/Wt2 [n][k] bf16; t kept in LDS (bf16).
// Block: 32 rows x 256 cols, 4 waves (wr: 16-row strip, wc: 128-col half),
// each wave 8 tiles of 16x16 via mfma_f32_16x16x32_bf16.
#define GBM 32

__global__ __launch_bounds__(256)
void gemm12_kernel(const ushort* __restrict__ A, const ushort* __restrict__ Wt1,
                   const float* __restrict__ b1, const ushort* __restrict__ Wt2,
                   const float* __restrict__ bnsc, const float* __restrict__ bnsh,
                   float* __restrict__ H, ushort* __restrict__ Hb, int nrows) {
    __shared__ __align__(16) ushort As[GBM][40];
    __shared__ __align__(16) ushort Bs[DIM][40];
    __shared__ __align__(16) ushort Ts[GBM][DIM + 8];
    int tx = threadIdx.x;
    int row0 = blockIdx.x * GBM;
    int wave = tx >> 6, lane = tx & 63, quad = lane >> 4, l16 = lane & 15;
    int wr = (wave >> 1) * 16;     // 0 or 16
    int wc = (wave & 1) * 128;     // 0 or 128
    int srow = tx >> 2;            // 0..63
    int skol = (tx & 3) * 8;       // 0,8,16,24

    f32x4 acc[8];
#pragma unroll
    for (int t = 0; t < 8; ++t) acc[t] = (f32x4){0.f, 0.f, 0.f, 0.f};

    // ---- GEMM1: t = relu(A@W1+b1) -> Ts (LDS) ----
    for (int k0 = 0; k0 < DIM; k0 += 32) {
        if (tx < 128) {
            int arow = row0 + srow;     // srow 0..31
            uint4 av = make_uint4(0u, 0u, 0u, 0u);
            if (arow < nrows) av = *(const uint4*)&A[(size_t)arow * DIM + k0 + skol];
            *(uint4*)&As[srow][skol] = av;
        }
#pragma unroll
        for (int j = 0; j < 4; ++j) {
            int r = srow + 64 * j;
            *(uint4*)&Bs[r][skol] = *(const uint4*)&Wt1[(size_t)r * DIM + k0 + skol];
        }
        __syncthreads();
        bf16x8 af = *(const bf16x8*)&As[wr + l16][quad * 8];
#pragma unroll
        for (int tj = 0; tj < 8; ++tj) {
            bf16x8 bf = *(const bf16x8*)&Bs[wc + tj * 16 + l16][quad * 8];
            acc[tj] = __builtin_amdgcn_mfma_f32_16x16x32_bf16(af, bf, acc[tj], 0, 0, 0);
        }
        __syncthreads();
    }
#pragma unroll
    for (int tj = 0; tj < 8; ++tj) {
        int col = wc + tj * 16 + l16;
        float bias = b1[col];
#pragma unroll
        for (int r = 0; r < 4; ++r) {
            int rl = wr + quad * 4 + r;
            Ts[rl][col] = f2bf(fmaxf(acc[tj][r] + bias, 0.f));
        }
    }
    __syncthreads();

    // ---- GEMM2: h = relu(bn(t@W2)) ----
#pragma unroll
    for (int t = 0; t < 8; ++t) acc[t] = (f32x4){0.f, 0.f, 0.f, 0.f};
    for (int k0 = 0; k0 < DIM; k0 += 32) {
#pragma unroll
        for (int j = 0; j < 4; ++j) {
            int r = srow + 64 * j;
            *(uint4*)&Bs[r][skol] = *(const uint4*)&Wt2[(size_t)r * DIM + k0 + skol];
        }
        __syncthreads();
        bf16x8 af = *(const bf16x8*)&Ts[wr + l16][k0 + quad * 8];
#pragma unroll
        for (int tj = 0; tj < 8; ++tj) {
            bf16x8 bf = *(const bf16x8*)&Bs[wc + tj * 16 + l16][quad * 8];
            acc[tj] = __builtin_amdgcn_mfma_f32_16x16x32_bf16(af, bf, acc[tj], 0, 0, 0);
        }
        __syncthreads();
    }
#pragma unroll
    for (int tj = 0; tj < 8; ++tj) {
        int col = wc + tj * 16 + l16;
        float s = bnsc[col], sh = bnsh[col];
#pragma unroll
        for (int r = 0; r < 4; ++r) {
            int row = row0 + wr + quad * 4 + r;
            if (row < nrows) {
                float v = fmaxf(acc[tj][r] * s + sh, 0.f);
                H[(size_t)row * DIM + col] = v;
                Hb[(size_t)row * DIM + col] = f2bf(v);
            }
        }
    }
}

// ---------------- pooling ----------------
__global__ __launch_bounds__(256)
void pool_kernel(const float* __restrict__ h, const int* __restrict__ batch,
                 float* __restrict__ pool, int* __restrict__ cnt,
                 float* __restrict__ out_h) {
    int i = blockIdx.x;
    int d = threadIdx.x;
    float v = h[i * DIM + d];
    out_h[i * DIM + d] = v;
    int b = batch[i];
    atomicAdd(&pool[b * DIM + d], v);
    if (d == 0) atomicAdd(&cnt[b], 1);
}

__global__ __launch_bounds__(256)
void final_kernel(const float* __restrict__ pool, const int* __restrict__ cnt,
                  float* __restrict__ out) {
    int g = blockIdx.x;
    int d = threadIdx.x;
    float c = (float)cnt[g];
    if (c < 1.f) c = 1.f;
    out[g * DIM + d] = pool[g * DIM + d] / c;
}

// ---------------- launch ----------------
extern "C" void kernel_launch(void* const* d_in, const int* in_sizes, int n_in,
                              void* d_out, int out_size, void* d_ws, size_t ws_size,
                              hipStream_t stream) {
    const int*   feat_id  = (const int*)d_in[0];
    const int*   ei       = (const int*)d_in[1];
    const int*   batch    = (const int*)d_in[2];
    const float* rwse     = (const float*)d_in[3];
    const int*   in_deg   = (const int*)d_in[4];
    const float* w_val    = (const float*)d_in[5];
    const float* b_val    = (const float*)d_in[6];
    const float* w_rwse   = (const float*)d_in[7];
    const float* b_rwse   = (const float*)d_in[8];
    const float* deg_emb  = (const float*)d_in[9];
    const float* mlp_w1   = (const float*)d_in[10];
    const float* mlp_b1   = (const float*)d_in[11];
    const float* mlp_w2   = (const float*)d_in[12];
    const float* mlp_b2   = (const float*)d_in[13];
    const float* bn_gamma = (const float*)d_in[14];
    const float* bn_beta  = (const float*)d_in[15];
    const float* bn_mean  = (const float*)d_in[16];
    const float* bn_var   = (const float*)d_in[17];
    const float* eps_gin  = (const float*)d_in[18];

    float* out = (float*)d_out;

    char* w = (char*)d_ws;
    float*  h   = (float*)w;                              // N*D f32
    ushort* hb  = (ushort*)(h + (size_t)N_NODES * DIM);   // N*D bf16
    ushort* y   = hb + (size_t)N_NODES * DIM;             // N*D bf16
    ushort* wt1 = y + (size_t)N_NODES * DIM;              // L*D*D bf16
    ushort* wt2 = wt1 + (size_t)N_LAYERS * DIM * DIM;     // L*D*D bf16
    int* cnt_arr = (int*)(wt2 + (size_t)N_LAYERS * DIM * DIM); // N
    int* cur     = cnt_arr + N_NODES;                     // N
    int* cs      = cur + N_NODES;                         // E
    float* pool  = (float*)(cs + N_EDGES);                // G*D
    int* gcnt    = (int*)(pool + N_GRAPHS * DIM);         // G
    float* bnsc  = (float*)(gcnt + N_GRAPHS);             // L*D
    float* bnsh  = bnsc + N_LAYERS * DIM;                 // L*D

    hipMemsetAsync(cnt_arr, 0, N_NODES * sizeof(int), stream);
    hipMemsetAsync(pool, 0, (N_GRAPHS * DIM + N_GRAPHS) * sizeof(float), stream);

    embed_kernel<<<N_NODES, 256, 0, stream>>>(feat_id, rwse, in_deg, w_val, b_val,
                                              w_rwse, b_rwse, deg_emb, h, hb);
    count_kernel<<<(N_EDGES + 255) / 256, 256, 0, stream>>>(ei, cnt_arr);
    scan_kernel<<<1, 1024, 0, stream>>>(cnt_arr, cur, N_NODES);
    fill_kernel<<<(N_EDGES + 255) / 256, 256, 0, stream>>>(ei, cur, cs);
    wconv_prep_kernel<<<dim3(65, 2, N_LAYERS), 256, 0, stream>>>(
        mlp_w1, mlp_w2, wt1, wt2,
        bn_gamma, bn_beta, bn_mean, bn_var, mlp_b2, bnsc, bnsh);

    int ggrid = (N_NODES + GBM - 1) / GBM;
    for (int l = 0; l < N_LAYERS; ++l) {
        agg_kernel<<<(N_NODES + 3) / 4, 256, 0, stream>>>(h, hb, cur, cs, eps_gin, l, y);
        gemm12_kernel<<<ggrid, 256, 0, stream>>>(y, wt1 + (size_t)l * DIM * DIM,
                                                 mlp_b1 + l * DIM,
                                                 wt2 + (size_t)l * DIM * DIM,
                                                 bnsc + l * DIM, bnsh + l * DIM,
                                                 h, hb, N_NODES);
    }

    pool_kernel<<<N_NODES, 256, 0, stream>>>(h, batch, pool, gcnt, out + N_GRAPHS * DIM);
    final_kernel<<<N_GRAPHS, 256, 0, stream>>>(pool, gcnt, out);
}

// Round 5
// 362.695 us; speedup vs baseline: 2.0722x; 1.1307x over previous
//
#include <hip/hip_runtime.h>
#include <hip/hip_bf16.h>

#define N_NODES 10000
#define N_EDGES 320000
#define DIM     256
#define N_LAYERS 5
#define N_GRAPHS 128
#define RWSE_K  16

typedef __bf16 bf16_t;
typedef bf16_t bf16x8 __attribute__((ext_vector_type(8)));
typedef float  f32x4  __attribute__((ext_vector_type(4)));

__device__ inline ushort f2bf(float f) {
    union { float f; unsigned u; } v; v.f = f;
    unsigned r = v.u + 0x7fff + ((v.u >> 16) & 1);
    return (ushort)(r >> 16);
}
__device__ inline float bfbits2f(unsigned hi16) {
    union { unsigned u; float f; } v; v.u = hi16;
    return v.f;
}

// ---------------- fused setup: embed + edge-count + weight conv + BN fold ----
// blocks [0,10000): embed node i
// blocks [10000,11250): count edges
// blocks [11250,11890): wconv tile
// blocks [11890,11895): BN prep layer
__global__ __launch_bounds__(256)
void setup_kernel(const int* __restrict__ feat_id,
                  const float* __restrict__ rwse,
                  const int* __restrict__ in_deg,
                  const float* __restrict__ w_val,
                  const float* __restrict__ b_val,
                  const float* __restrict__ w_rwse,
                  const float* __restrict__ b_rwse,
                  const float* __restrict__ deg_emb,
                  float* __restrict__ h, ushort* __restrict__ hb,
                  const int* __restrict__ ei, int* __restrict__ cnt_arr,
                  const float* __restrict__ w1, const float* __restrict__ w2,
                  ushort* __restrict__ wt1, ushort* __restrict__ wt2,
                  const float* __restrict__ gamma, const float* __restrict__ beta,
                  const float* __restrict__ mean, const float* __restrict__ var,
                  const float* __restrict__ b2, float* __restrict__ scale,
                  float* __restrict__ shift) {
    __shared__ float r[RWSE_K];
    __shared__ float t[32][33];
    int b = blockIdx.x;
    int tid = threadIdx.x;
    if (b < N_NODES) {
        int i = b, d = tid;
        if (d < RWSE_K) r[d] = rwse[i * RWSE_K + d];
        __syncthreads();
        int hid = feat_id[i] & (DIM - 1);
        int dg = in_deg[i];
        dg = dg < 0 ? 0 : (dg > 1000 ? 1000 : dg);
        float v = w_val[hid * DIM + d] + b_val[d] + b_rwse[d] + deg_emb[dg * DIM + d];
#pragma unroll
        for (int k = 0; k < RWSE_K; ++k) v += r[k] * w_rwse[k * DIM + d];
        h[i * DIM + d] = v;
        hb[i * DIM + d] = f2bf(v);
    } else if (b < 11250) {
        int e = (b - N_NODES) * 256 + tid;
        if (e < N_EDGES) atomicAdd(&cnt_arr[ei[N_EDGES + e]], 1);
    } else if (b < 11890) {
        int w_id = b - 11250;
        int l = w_id >> 7;            // /128
        int rem = w_id & 127;
        int mat = rem >> 6;           // /64
        int tile = rem & 63;
        const float* W  = (mat ? w2  : w1)  + (size_t)l * DIM * DIM;
        ushort*      Wt = (mat ? wt2 : wt1) + (size_t)l * DIM * DIM;
        int k0 = (tile >> 3) * 32, n0 = (tile & 7) * 32;
        int tx = tid & 31, ty = tid >> 5;
#pragma unroll
        for (int j = 0; j < 4; ++j)
            t[ty + j * 8][tx] = W[(k0 + ty + j * 8) * DIM + n0 + tx];
        __syncthreads();
#pragma unroll
        for (int j = 0; j < 4; ++j)
            Wt[(n0 + ty + j * 8) * DIM + k0 + tx] = f2bf(t[tx][ty + j * 8]);
    } else {
        int l = b - 11890;
        int idx = l * DIM + tid;
        float s = gamma[idx] * rsqrtf(var[idx] + 1e-5f);
        scale[idx] = s;
        shift[idx] = beta[idx] + (b2[idx] - mean[idx]) * s;
    }
}

// exclusive scan of cnt_arr into cur (single block, wave-shuffle based)
__global__ __launch_bounds__(1024)
void scan_kernel(const int* __restrict__ cnt_arr, int* __restrict__ cur, int n) {
    __shared__ int wsum[16];
    __shared__ int carry_sh;
    int tid = threadIdx.x, wave = tid >> 6, lane = tid & 63;
    if (tid == 0) carry_sh = 0;
    __syncthreads();
    for (int base = 0; base < n; base += 1024) {
        int idx = base + tid;
        int v = (idx < n) ? cnt_arr[idx] : 0;
        int s = v;
#pragma unroll
        for (int off = 1; off < 64; off <<= 1) {
            int t = __shfl_up(s, off, 64);
            if (lane >= off) s += t;
        }
        if (lane == 63) wsum[wave] = s;
        __syncthreads();
        if (wave == 0) {
            int ws = (lane < 16) ? wsum[lane] : 0;
#pragma unroll
            for (int off = 1; off < 16; off <<= 1) {
                int t = __shfl_up(ws, off, 64);
                if (lane >= off) ws += t;
            }
            if (lane < 16) wsum[lane] = ws;
        }
        __syncthreads();
        int excl = s - v + (wave ? wsum[wave - 1] : 0) + carry_sh;
        if (idx < n) cur[idx] = excl;
        __syncthreads();
        if (tid == 0) carry_sh += wsum[15];
        __syncthreads();
    }
}

// fill: atomically bump cur[d]; after this kernel cur[i] == end offset of node i
__global__ __launch_bounds__(256)
void fill_kernel(const int* __restrict__ ei, int* __restrict__ cur,
                 int* __restrict__ cs) {
    int e = blockIdx.x * 256 + threadIdx.x;
    if (e < N_EDGES) {
        int d = ei[N_EDGES + e];
        int p = atomicAdd(&cur[d], 1);
        cs[p] = ei[e];
    }
}

// ---------------- aggregation ----------------
// one wave per node; uint4 gather: lanes 0-31 -> neighbor j, lanes 32-63 -> j+1;
// each lane covers 8 channels; cross-half combine via shfl_xor(32).
__global__ __launch_bounds__(256)
void agg_kernel(const float* __restrict__ h, const ushort* __restrict__ hb,
                const int* __restrict__ cur, const int* __restrict__ cs,
                const float* __restrict__ eps_gin, int layer,
                ushort* __restrict__ y) {
    int wave = threadIdx.x >> 6;
    int lane = threadIdx.x & 63;
    int half = lane >> 5;
    int sl   = lane & 31;          // uint4 chunk (8 channels) within row
    int i = blockIdx.x * 4 + wave;
    if (i >= N_NODES) return;
    const uint4* hb4 = (const uint4*)hb;   // row = 32 uint4
    float acc[8];
#pragma unroll
    for (int t = 0; t < 8; ++t) acc[t] = 0.f;

    int e0 = i ? cur[i - 1] : 0;
    int e1 = cur[i];
    for (int base = e0; base < e1; base += 64) {
        int rem = e1 - base;
        int cnt = rem < 64 ? rem : 64;
        int idx = (base + lane < e1) ? cs[base + lane] : 0;
        int j = 0;
        for (; j + 8 <= cnt; j += 8) {
            int s0 = __shfl(idx, j + half, 64);
            int s1 = __shfl(idx, j + 2 + half, 64);
            int s2 = __shfl(idx, j + 4 + half, 64);
            int s3 = __shfl(idx, j + 6 + half, 64);
            uint4 v0 = hb4[(size_t)s0 * 32 + sl];
            uint4 v1 = hb4[(size_t)s1 * 32 + sl];
            uint4 v2 = hb4[(size_t)s2 * 32 + sl];
            uint4 v3 = hb4[(size_t)s3 * 32 + sl];
            acc[0] += bfbits2f(v0.x << 16); acc[1] += bfbits2f(v0.x & 0xffff0000u);
            acc[2] += bfbits2f(v0.y << 16); acc[3] += bfbits2f(v0.y & 0xffff0000u);
            acc[4] += bfbits2f(v0.z << 16); acc[5] += bfbits2f(v0.z & 0xffff0000u);
            acc[6] += bfbits2f(v0.w << 16); acc[7] += bfbits2f(v0.w & 0xffff0000u);
            acc[0] += bfbits2f(v1.x << 16); acc[1] += bfbits2f(v1.x & 0xffff0000u);
            acc[2] += bfbits2f(v1.y << 16); acc[3] += bfbits2f(v1.y & 0xffff0000u);
            acc[4] += bfbits2f(v1.z << 16); acc[5] += bfbits2f(v1.z & 0xffff0000u);
            acc[6] += bfbits2f(v1.w << 16); acc[7] += bfbits2f(v1.w & 0xffff0000u);
            acc[0] += bfbits2f(v2.x << 16); acc[1] += bfbits2f(v2.x & 0xffff0000u);
            acc[2] += bfbits2f(v2.y << 16); acc[3] += bfbits2f(v2.y & 0xffff0000u);
            acc[4] += bfbits2f(v2.z << 16); acc[5] += bfbits2f(v2.z & 0xffff0000u);
            acc[6] += bfbits2f(v2.w << 16); acc[7] += bfbits2f(v2.w & 0xffff0000u);
            acc[0] += bfbits2f(v3.x << 16); acc[1] += bfbits2f(v3.x & 0xffff0000u);
            acc[2] += bfbits2f(v3.y << 16); acc[3] += bfbits2f(v3.y & 0xffff0000u);
            acc[4] += bfbits2f(v3.z << 16); acc[5] += bfbits2f(v3.z & 0xffff0000u);
            acc[6] += bfbits2f(v3.w << 16); acc[7] += bfbits2f(v3.w & 0xffff0000u);
        }
        for (; j + 2 <= cnt; j += 2) {
            int s = __shfl(idx, j + half, 64);
            uint4 v = hb4[(size_t)s * 32 + sl];
            acc[0] += bfbits2f(v.x << 16); acc[1] += bfbits2f(v.x & 0xffff0000u);
            acc[2] += bfbits2f(v.y << 16); acc[3] += bfbits2f(v.y & 0xffff0000u);
            acc[4] += bfbits2f(v.z << 16); acc[5] += bfbits2f(v.z & 0xffff0000u);
            acc[6] += bfbits2f(v.w << 16); acc[7] += bfbits2f(v.w & 0xffff0000u);
        }
        if (j < cnt) {                       // odd leftover: half 0 only
            int s = __shfl(idx, j, 64);
            if (half == 0) {
                uint4 v = hb4[(size_t)s * 32 + sl];
                acc[0] += bfbits2f(v.x << 16); acc[1] += bfbits2f(v.x & 0xffff0000u);
                acc[2] += bfbits2f(v.y << 16); acc[3] += bfbits2f(v.y & 0xffff0000u);
                acc[4] += bfbits2f(v.z << 16); acc[5] += bfbits2f(v.z & 0xffff0000u);
                acc[6] += bfbits2f(v.w << 16); acc[7] += bfbits2f(v.w & 0xffff0000u);
            }
        }
    }
    // combine halves
#pragma unroll
    for (int t = 0; t < 8; ++t) acc[t] += __shfl_xor(acc[t], 32, 64);
    if (half == 0) {
        float sc = 1.0f + eps_gin[layer];
        const float4* h4 = (const float4*)h;
        float4 a0 = h4[(size_t)i * 64 + sl * 2];
        float4 a1 = h4[(size_t)i * 64 + sl * 2 + 1];
        acc[0] += a0.x * sc; acc[1] += a0.y * sc;
        acc[2] += a0.z * sc; acc[3] += a0.w * sc;
        acc[4] += a1.x * sc; acc[5] += a1.y * sc;
        acc[6] += a1.z * sc; acc[7] += a1.w * sc;
        uint4 o;
        o.x = (uint)f2bf(acc[0]) | ((uint)f2bf(acc[1]) << 16);
        o.y = (uint)f2bf(acc[2]) | ((uint)f2bf(acc[3]) << 16);
        o.z = (uint)f2bf(acc[4]) | ((uint)f2bf(acc[5]) << 16);
        o.w = (uint)f2bf(acc[6]) | ((uint)f2bf(acc[7]) << 16);
        ((uint4*)y)[(size_t)i * 32 + sl] = o;
    }
}

// ---------------- fused MLP: H = ReLU(BN(ReLU(A@W1+b1)@W2)) ----------------
#define GBM 32

__global__ __launch_bounds__(256)
void gemm12_kernel(const ushort* __restrict__ A, const ushort* __restrict__ Wt1,
                   const float* __restrict__ b1, const ushort* __restrict__ Wt2,
                   const float* __restrict__ bnsc, const float* __restrict__ bnsh,
                   float* __restrict__ H, ushort* __restrict__ Hb, int nrows) {
    __shared__ __align__(16) ushort As[GBM][40];
    __shared__ __align__(16) ushort Bs[DIM][40];
    __shared__ __align__(16) ushort Ts[GBM][DIM + 8];
    int tx = threadIdx.x;
    int row0 = blockIdx.x * GBM;
    int wave = tx >> 6, lane = tx & 63, quad = lane >> 4, l16 = lane & 15;
    int wr = (wave >> 1) * 16;
    int wc = (wave & 1) * 128;
    int srow = tx >> 2;
    int skol = (tx & 3) * 8;

    f32x4 acc[8];
#pragma unroll
    for (int t = 0; t < 8; ++t) acc[t] = (f32x4){0.f, 0.f, 0.f, 0.f};

    for (int k0 = 0; k0 < DIM; k0 += 32) {
        if (tx < 128) {
            int arow = row0 + srow;
            uint4 av = make_uint4(0u, 0u, 0u, 0u);
            if (arow < nrows) av = *(const uint4*)&A[(size_t)arow * DIM + k0 + skol];
            *(uint4*)&As[srow][skol] = av;
        }
#pragma unroll
        for (int j = 0; j < 4; ++j) {
            int r = srow + 64 * j;
            *(uint4*)&Bs[r][skol] = *(const uint4*)&Wt1[(size_t)r * DIM + k0 + skol];
        }
        __syncthreads();
        bf16x8 af = *(const bf16x8*)&As[wr + l16][quad * 8];
#pragma unroll
        for (int tj = 0; tj < 8; ++tj) {
            bf16x8 bf = *(const bf16x8*)&Bs[wc + tj * 16 + l16][quad * 8];
            acc[tj] = __builtin_amdgcn_mfma_f32_16x16x32_bf16(af, bf, acc[tj], 0, 0, 0);
        }
        __syncthreads();
    }
#pragma unroll
    for (int tj = 0; tj < 8; ++tj) {
        int col = wc + tj * 16 + l16;
        float bias = b1[col];
#pragma unroll
        for (int r = 0; r < 4; ++r) {
            int rl = wr + quad * 4 + r;
            Ts[rl][col] = f2bf(fmaxf(acc[tj][r] + bias, 0.f));
        }
    }
    __syncthreads();

#pragma unroll
    for (int t = 0; t < 8; ++t) acc[t] = (f32x4){0.f, 0.f, 0.f, 0.f};
    for (int k0 = 0; k0 < DIM; k0 += 32) {
#pragma unroll
        for (int j = 0; j < 4; ++j) {
            int r = srow + 64 * j;
            *(uint4*)&Bs[r][skol] = *(const uint4*)&Wt2[(size_t)r * DIM + k0 + skol];
        }
        __syncthreads();
        bf16x8 af = *(const bf16x8*)&Ts[wr + l16][k0 + quad * 8];
#pragma unroll
        for (int tj = 0; tj < 8; ++tj) {
            bf16x8 bf = *(const bf16x8*)&Bs[wc + tj * 16 + l16][quad * 8];
            acc[tj] = __builtin_amdgcn_mfma_f32_16x16x32_bf16(af, bf, acc[tj], 0, 0, 0);
        }
        __syncthreads();
    }
#pragma unroll
    for (int tj = 0; tj < 8; ++tj) {
        int col = wc + tj * 16 + l16;
        float s = bnsc[col], sh = bnsh[col];
#pragma unroll
        for (int r = 0; r < 4; ++r) {
            int row = row0 + wr + quad * 4 + r;
            if (row < nrows) {
                float v = fmaxf(acc[tj][r] * s + sh, 0.f);
                H[(size_t)row * DIM + col] = v;
                Hb[(size_t)row * DIM + col] = f2bf(v);
            }
        }
    }
}

// ---------------- pooling: batch is sorted -> per-graph contiguous range ----
__global__ __launch_bounds__(256)
void pool_kernel(const float* __restrict__ hfin, const int* __restrict__ batch,
                 float* __restrict__ out) {
    int g = blockIdx.x;
    int d = threadIdx.x;
    int l = 0, r = N_NODES;
    while (l < r) { int m = (l + r) >> 1; if (batch[m] < g) l = m + 1; else r = m; }
    int lo = l;
    r = N_NODES;
    while (l < r) { int m = (l + r) >> 1; if (batch[m] < g + 1) l = m + 1; else r = m; }
    int hi = l;
    float a0 = 0.f, a1 = 0.f, a2 = 0.f, a3 = 0.f;
    int i = lo;
    for (; i + 4 <= hi; i += 4) {
        a0 += hfin[(size_t)i * DIM + d];
        a1 += hfin[(size_t)(i + 1) * DIM + d];
        a2 += hfin[(size_t)(i + 2) * DIM + d];
        a3 += hfin[(size_t)(i + 3) * DIM + d];
    }
    for (; i < hi; ++i) a0 += hfin[(size_t)i * DIM + d];
    float c = (float)(hi - lo);
    if (c < 1.f) c = 1.f;
    out[g * DIM + d] = ((a0 + a1) + (a2 + a3)) / c;
}

// ---------------- launch ----------------
extern "C" void kernel_launch(void* const* d_in, const int* in_sizes, int n_in,
                              void* d_out, int out_size, void* d_ws, size_t ws_size,
                              hipStream_t stream) {
    const int*   feat_id  = (const int*)d_in[0];
    const int*   ei       = (const int*)d_in[1];
    const int*   batch    = (const int*)d_in[2];
    const float* rwse     = (const float*)d_in[3];
    const int*   in_deg   = (const int*)d_in[4];
    const float* w_val    = (const float*)d_in[5];
    const float* b_val    = (const float*)d_in[6];
    const float* w_rwse   = (const float*)d_in[7];
    const float* b_rwse   = (const float*)d_in[8];
    const float* deg_emb  = (const float*)d_in[9];
    const float* mlp_w1   = (const float*)d_in[10];
    const float* mlp_b1   = (const float*)d_in[11];
    const float* mlp_w2   = (const float*)d_in[12];
    const float* mlp_b2   = (const float*)d_in[13];
    const float* bn_gamma = (const float*)d_in[14];
    const float* bn_beta  = (const float*)d_in[15];
    const float* bn_mean  = (const float*)d_in[16];
    const float* bn_var   = (const float*)d_in[17];
    const float* eps_gin  = (const float*)d_in[18];

    float* out = (float*)d_out;
    float* out_h = out + N_GRAPHS * DIM;   // [N,D] final h, written by last gemm12

    char* w = (char*)d_ws;
    float*  h   = (float*)w;                              // N*D f32
    ushort* hb  = (ushort*)(h + (size_t)N_NODES * DIM);   // N*D bf16
    ushort* y   = hb + (size_t)N_NODES * DIM;             // N*D bf16
    ushort* wt1 = y + (size_t)N_NODES * DIM;              // L*D*D bf16
    ushort* wt2 = wt1 + (size_t)N_LAYERS * DIM * DIM;     // L*D*D bf16
    int* cnt_arr = (int*)(wt2 + (size_t)N_LAYERS * DIM * DIM); // N
    int* cur     = cnt_arr + N_NODES;                     // N
    int* cs      = cur + N_NODES;                         // E
    float* bnsc  = (float*)(cs + N_EDGES);                // L*D
    float* bnsh  = bnsc + N_LAYERS * DIM;                 // L*D

    hipMemsetAsync(cnt_arr, 0, N_NODES * sizeof(int), stream);

    setup_kernel<<<11895, 256, 0, stream>>>(
        feat_id, rwse, in_deg, w_val, b_val, w_rwse, b_rwse, deg_emb, h, hb,
        ei, cnt_arr, mlp_w1, mlp_w2, wt1, wt2,
        bn_gamma, bn_beta, bn_mean, bn_var, mlp_b2, bnsc, bnsh);
    scan_kernel<<<1, 1024, 0, stream>>>(cnt_arr, cur, N_NODES);
    fill_kernel<<<(N_EDGES + 255) / 256, 256, 0, stream>>>(ei, cur, cs);

    int ggrid = (N_NODES + GBM - 1) / GBM;
    for (int l = 0; l < N_LAYERS; ++l) {
        agg_kernel<<<(N_NODES + 3) / 4, 256, 0, stream>>>(h, hb, cur, cs, eps_gin, l, y);
        float* Hdst = (l == N_LAYERS - 1) ? out_h : h;
        gemm12_kernel<<<ggrid, 256, 0, stream>>>(y, wt1 + (size_t)l * DIM * DIM,
                                                 mlp_b1 + l * DIM,
                                                 wt2 + (size_t)l * DIM * DIM,
                                                 bnsc + l * DIM, bnsh + l * DIM,
                                                 Hdst, hb, N_NODES);
    }

    pool_kernel<<<N_GRAPHS, 256, 0, stream>>>(out_h, batch, out);
}